// Round 1
// baseline (4526.167 us; speedup 1.0000x reference)
//
#include <hip/hip_runtime.h>

#define TPB 256
constexpr int DIN = 47;
constexpr int HID = 128;
constexpr int LAT = 64;
constexpr int GG  = 1024;

// ---------------- embed: out = relu(x @ W_emb + b), x:[n,47] W:[47,128] ----------------
__global__ __launch_bounds__(256) void embed_kernel(
    const float* __restrict__ x, const float* __restrict__ W,
    const float* __restrict__ b, float* __restrict__ out, int n) {
  __shared__ float Wl[DIN * HID];
  __shared__ float bl[HID];
  __shared__ float xs[8][48];           // 47 padded to 48
  const int tid = threadIdx.x;
  for (int i = tid; i < DIN * HID; i += TPB) Wl[i] = W[i];
  if (tid < HID) bl[tid] = b[tid];
  const int tx = tid & 31, slot = tid >> 5;   // 8 nodes/block, 32 threads/node, 4 cols each
  const float4* Wl4 = (const float4*)Wl;
  for (int base = blockIdx.x * 8; base < n; base += gridDim.x * 8) {
    __syncthreads();
    for (int i = tid; i < 8 * DIN; i += TPB) {
      int s = i / DIN, k = i - s * DIN;
      int node = base + s;
      xs[s][k] = (node < n) ? x[node * DIN + k] : 0.f;
    }
    __syncthreads();
    int node = base + slot;
    if (node < n) {
      float4 acc = ((const float4*)bl)[tx];
      #pragma unroll
      for (int k = 0; k < DIN; ++k) {
        float xv = xs[slot][k];
        float4 w = Wl4[k * 32 + tx];
        acc.x += xv * w.x; acc.y += xv * w.y; acc.z += xv * w.z; acc.w += xv * w.w;
      }
      acc.x = fmaxf(acc.x, 0.f); acc.y = fmaxf(acc.y, 0.f);
      acc.z = fmaxf(acc.z, 0.f); acc.w = fmaxf(acc.w, 0.f);
      ((float4*)out)[node * 32 + tx] = acc;
    }
  }
}

// ---------------- lin: out[n,OD] = h[n,128] @ W[128,OD] (no bias) ----------------
template <int OD>
__global__ __launch_bounds__(256) void lin_kernel(
    const float* __restrict__ h, const float* __restrict__ W,
    float* __restrict__ out, int n) {
  constexpr int Q  = OD / 4;     // float4-cols per node
  constexpr int NS = TPB / Q;    // node slots per block (8 or 16)
  __shared__ float Wl[HID * OD];
  __shared__ float xs[NS][HID];
  const int tid = threadIdx.x;
  for (int i = tid; i < HID * OD; i += TPB) Wl[i] = W[i];
  const int tx = tid & (Q - 1), slot = tid / Q;
  const float4* Wl4 = (const float4*)Wl;
  const float4* h4  = (const float4*)h;
  for (int base = blockIdx.x * NS; base < n; base += gridDim.x * NS) {
    __syncthreads();
    for (int i = tid; i < NS * 32; i += TPB) {   // stage NS rows of 128 (32 float4 each)
      int s = i >> 5, q = i & 31;
      int node = base + s;
      ((float4*)xs)[i] = (node < n) ? h4[(size_t)node * 32 + q] : make_float4(0, 0, 0, 0);
    }
    __syncthreads();
    int node = base + slot;
    if (node < n) {
      float4 acc = make_float4(0, 0, 0, 0);
      #pragma unroll 8
      for (int k = 0; k < HID; ++k) {
        float xv = xs[slot][k];
        float4 w = Wl4[k * Q + tx];
        acc.x += xv * w.x; acc.y += xv * w.y; acc.z += xv * w.z; acc.w += xv * w.w;
      }
      ((float4*)out)[(size_t)node * Q + tx] = acc;
    }
  }
}

// ---------------- degree / dinv ----------------
__global__ void deg_kernel(const int* __restrict__ dst, float* __restrict__ deg, int e) {
  int i = blockIdx.x * TPB + threadIdx.x;
  if (i < e) atomicAdd(&deg[dst[i]], 1.f);
}
__global__ void dinv_kernel(float* __restrict__ deg, int n) {
  int i = blockIdx.x * TPB + threadIdx.x;
  if (i < n) deg[i] = rsqrtf(deg[i] + 1.f);
}

// ---------------- edge aggregation: agg[dst] += hlin[src] * dinv[src]*dinv[dst] ----------------
template <int OD>
__global__ __launch_bounds__(256) void agg_kernel(
    const float* __restrict__ hlin, const int* __restrict__ src,
    const int* __restrict__ dst, const float* __restrict__ dinv,
    float* __restrict__ agg, int e) {
  constexpr int Q = OD / 4;
  int i = blockIdx.x * TPB + threadIdx.x;
  if (i >= e * Q) return;
  int ed = i / Q, q = i - ed * Q;
  int s = src[ed], d = dst[ed];
  float w = dinv[s] * dinv[d];
  float4 v = ((const float4*)hlin)[(size_t)s * Q + q];
  float* p = agg + (size_t)d * OD + q * 4;
  atomicAdd(p + 0, v.x * w);
  atomicAdd(p + 1, v.y * w);
  atomicAdd(p + 2, v.z * w);
  atomicAdd(p + 3, v.w * w);
}

// ---------------- finalize: h = relu(agg + hlin*dinv^2 + b), in place over agg ----------------
template <int OD>
__global__ void finalize_kernel(float* __restrict__ agg, const float* __restrict__ hlin,
                                const float* __restrict__ b, const float* __restrict__ dinv,
                                int n) {
  int i = blockIdx.x * TPB + threadIdx.x;
  if (i >= n * OD) return;
  int node = i / OD, c = i - node * OD;
  float di = dinv[node];
  float v = agg[i] + hlin[i] * (di * di) + b[c];
  agg[i] = fmaxf(v, 0.f);
}

// ---------------- pool ----------------
__global__ void pool_kernel(const float* __restrict__ h, const int* __restrict__ batch,
                            float* __restrict__ gsum, float* __restrict__ gcnt, int n) {
  int i = blockIdx.x * TPB + threadIdx.x;
  if (i >= n * 16) return;               // 16 float4 per node (64 cols)
  int node = i >> 4, q = i & 15;
  int g = batch[node];
  float4 v = ((const float4*)h)[i];
  float* p = gsum + (size_t)g * LAT + q * 4;
  atomicAdd(p + 0, v.x); atomicAdd(p + 1, v.y);
  atomicAdd(p + 2, v.z); atomicAdd(p + 3, v.w);
  if (q == 0) atomicAdd(&gcnt[g], 1.f);
}

__global__ void div_kernel(const float* __restrict__ gsum, const float* __restrict__ gcnt,
                           float* __restrict__ out, int total) {
  int i = blockIdx.x * TPB + threadIdx.x;
  if (i < total) out[i] = gsum[i] / fmaxf(gcnt[i >> 6], 1.f);
}

extern "C" void kernel_launch(void* const* d_in, const int* in_sizes, int n_in,
                              void* d_out, int out_size, void* d_ws, size_t ws_size,
                              hipStream_t stream) {
  const float* x     = (const float*)d_in[0];
  const float* W_emb = (const float*)d_in[1];
  const float* b_emb = (const float*)d_in[2];
  const float* W1    = (const float*)d_in[3];
  const float* b1    = (const float*)d_in[4];
  const float* W2    = (const float*)d_in[5];
  const float* b2    = (const float*)d_in[6];
  const int*   ei    = (const int*)d_in[7];
  const int*   batch = (const int*)d_in[8];
  const int n = in_sizes[8];
  const int e = in_sizes[7] / 2;
  const int* srcp = ei;
  const int* dstp = ei + e;
  float* out = (float*)d_out;

  char* ws = (char*)d_ws;
  size_t off = 0;
  auto alloc = [&](size_t bytes) {
    void* p = ws + off;
    off += (bytes + 255) & ~(size_t)255;
    return p;
  };
  float* bufA = (float*)alloc((size_t)n * HID * 4);
  float* bufB = (float*)alloc((size_t)n * HID * 4);
  float* dinv = (float*)alloc((size_t)n * 4);
  float* gsum = (float*)alloc((size_t)GG * LAT * 4);
  float* gcnt = (float*)alloc((size_t)GG * 4);

  hipMemsetAsync(dinv, 0, (size_t)n * 4, stream);
  hipMemsetAsync(gsum, 0, (size_t)GG * LAT * 4, stream);
  hipMemsetAsync(gcnt, 0, (size_t)GG * 4, stream);

  // h0 = relu(x @ W_emb + b_emb)  -> bufA
  embed_kernel<<<2048, TPB, 0, stream>>>(x, W_emb, b_emb, bufA, n);
  // degrees -> dinv
  deg_kernel<<<(e + TPB - 1) / TPB, TPB, 0, stream>>>(dstp, dinv, e);
  dinv_kernel<<<(n + TPB - 1) / TPB, TPB, 0, stream>>>(dinv, n);

  // conv1: lin -> bufB; agg -> bufA (zeroed); finalize in place -> bufA = h1
  lin_kernel<HID><<<2048, TPB, 0, stream>>>(bufA, W1, bufB, n);
  hipMemsetAsync(bufA, 0, (size_t)n * HID * 4, stream);
  agg_kernel<HID><<<(e * (HID / 4) + TPB - 1) / TPB, TPB, 0, stream>>>(
      bufB, srcp, dstp, dinv, bufA, e);
  finalize_kernel<HID><<<(n * HID + TPB - 1) / TPB, TPB, 0, stream>>>(
      bufA, bufB, b1, dinv, n);

  // conv2: lin -> bufB (n x 64); agg -> bufA (zeroed n x 64); finalize -> bufA = h2
  lin_kernel<LAT><<<2048, TPB, 0, stream>>>(bufA, W2, bufB, n);
  hipMemsetAsync(bufA, 0, (size_t)n * LAT * 4, stream);
  agg_kernel<LAT><<<(e * (LAT / 4) + TPB - 1) / TPB, TPB, 0, stream>>>(
      bufB, srcp, dstp, dinv, bufA, e);
  finalize_kernel<LAT><<<(n * LAT + TPB - 1) / TPB, TPB, 0, stream>>>(
      bufA, bufB, b2, dinv, n);

  // mean pool
  pool_kernel<<<(n * 16 + TPB - 1) / TPB, TPB, 0, stream>>>(bufA, batch, gsum, gcnt, n);
  div_kernel<<<(GG * LAT + TPB - 1) / TPB, TPB, 0, stream>>>(gsum, gcnt, out, GG * LAT);
}

// Round 2
// 705.719 us; speedup vs baseline: 6.4136x; 6.4136x over previous
//
#include <hip/hip_runtime.h>

#define TPB 256
constexpr int DIN = 47;
constexpr int HID = 128;
constexpr int LAT = 64;
constexpr int GG  = 1024;

// ---------------- embed: out = relu(x @ W_emb + b), x:[n,47] W:[47,128] ----------------
__global__ __launch_bounds__(256) void embed_kernel(
    const float* __restrict__ x, const float* __restrict__ W,
    const float* __restrict__ b, float* __restrict__ out, int n) {
  __shared__ float Wl[DIN * HID];
  __shared__ float bl[HID];
  __shared__ float xs[8][48];
  const int tid = threadIdx.x;
  for (int i = tid; i < DIN * HID; i += TPB) Wl[i] = W[i];
  if (tid < HID) bl[tid] = b[tid];
  const int tx = tid & 31, slot = tid >> 5;
  const float4* Wl4 = (const float4*)Wl;
  for (int base = blockIdx.x * 8; base < n; base += gridDim.x * 8) {
    __syncthreads();
    for (int i = tid; i < 8 * DIN; i += TPB) {
      int s = i / DIN, k = i - s * DIN;
      int node = base + s;
      xs[s][k] = (node < n) ? x[node * DIN + k] : 0.f;
    }
    __syncthreads();
    int node = base + slot;
    if (node < n) {
      float4 acc = ((const float4*)bl)[tx];
      #pragma unroll
      for (int k = 0; k < DIN; ++k) {
        float xv = xs[slot][k];
        float4 w = Wl4[k * 32 + tx];
        acc.x += xv * w.x; acc.y += xv * w.y; acc.z += xv * w.z; acc.w += xv * w.w;
      }
      acc.x = fmaxf(acc.x, 0.f); acc.y = fmaxf(acc.y, 0.f);
      acc.z = fmaxf(acc.z, 0.f); acc.w = fmaxf(acc.w, 0.f);
      ((float4*)out)[node * 32 + tx] = acc;
    }
  }
}

// ---------------- lin: out[n,OD] = h[n,128] @ W[128,OD] (no bias) ----------------
template <int OD>
__global__ __launch_bounds__(256) void lin_kernel(
    const float* __restrict__ h, const float* __restrict__ W,
    float* __restrict__ out, int n) {
  constexpr int Q  = OD / 4;
  constexpr int NS = TPB / Q;
  __shared__ float Wl[HID * OD];
  __shared__ float xs[NS][HID];
  const int tid = threadIdx.x;
  for (int i = tid; i < HID * OD; i += TPB) Wl[i] = W[i];
  const int tx = tid & (Q - 1), slot = tid / Q;
  const float4* Wl4 = (const float4*)Wl;
  const float4* h4  = (const float4*)h;
  for (int base = blockIdx.x * NS; base < n; base += gridDim.x * NS) {
    __syncthreads();
    for (int i = tid; i < NS * 32; i += TPB) {
      int s = i >> 5, q = i & 31;
      int node = base + s;
      ((float4*)xs)[i] = (node < n) ? h4[(size_t)node * 32 + q] : make_float4(0, 0, 0, 0);
    }
    __syncthreads();
    int node = base + slot;
    if (node < n) {
      float4 acc = make_float4(0, 0, 0, 0);
      #pragma unroll 8
      for (int k = 0; k < HID; ++k) {
        float xv = xs[slot][k];
        float4 w = Wl4[k * Q + tx];
        acc.x += xv * w.x; acc.y += xv * w.y; acc.z += xv * w.z; acc.w += xv * w.w;
      }
      ((float4*)out)[(size_t)node * Q + tx] = acc;
    }
  }
}

// ---------------- CSR build ----------------
__global__ void deg_count_kernel(const int* __restrict__ dst, int* __restrict__ cnt, int e) {
  int i = blockIdx.x * TPB + threadIdx.x;
  if (i < e) atomicAdd(&cnt[dst[i]], 1);
}

__global__ void dinv_kernel(const int* __restrict__ cnt, float* __restrict__ dinv, int n) {
  int i = blockIdx.x * TPB + threadIdx.x;
  if (i < n) dinv[i] = rsqrtf((float)cnt[i] + 1.f);
}

// block-local exclusive scan; block totals to bsum
__global__ void scan1_kernel(const int* __restrict__ cnt, int* __restrict__ rowptr,
                             int* __restrict__ bsum, int n) {
  __shared__ int sh[TPB];
  int i = blockIdx.x * TPB + threadIdx.x;
  int v = (i < n) ? cnt[i] : 0;
  sh[threadIdx.x] = v;
  __syncthreads();
  for (int off = 1; off < TPB; off <<= 1) {
    int t = (threadIdx.x >= off) ? sh[threadIdx.x - off] : 0;
    __syncthreads();
    sh[threadIdx.x] += t;
    __syncthreads();
  }
  if (i < n) rowptr[i] = sh[threadIdx.x] - v;      // exclusive within block
  if (threadIdx.x == TPB - 1) bsum[blockIdx.x] = sh[threadIdx.x];
}

// single-block scan of block totals (handles any nb via 512-chunks + carry)
__global__ void scan2_kernel(int* __restrict__ bsum, int nb) {
  __shared__ int sh[512];
  __shared__ int carry;
  if (threadIdx.x == 0) carry = 0;
  __syncthreads();
  for (int base = 0; base < nb; base += 512) {
    int i = base + threadIdx.x;
    int v = (i < nb) ? bsum[i] : 0;
    sh[threadIdx.x] = v;
    __syncthreads();
    for (int off = 1; off < 512; off <<= 1) {
      int t = (threadIdx.x >= off) ? sh[threadIdx.x - off] : 0;
      __syncthreads();
      sh[threadIdx.x] += t;
      __syncthreads();
    }
    if (i < nb) bsum[i] = carry + sh[threadIdx.x] - v;  // exclusive
    __syncthreads();
    if (threadIdx.x == 0) carry += sh[511];
    __syncthreads();
  }
}

__global__ void scan3_kernel(int* __restrict__ rowptr, const int* __restrict__ bsum,
                             int n, int e) {
  int i = blockIdx.x * TPB + threadIdx.x;
  if (i < n) rowptr[i] += bsum[blockIdx.x];
  if (i == 0) rowptr[n] = e;
}

__global__ void build_csr_kernel(const int* __restrict__ src, const int* __restrict__ dst,
                                 const int* __restrict__ rowptr, int* __restrict__ fill,
                                 const float* __restrict__ dinv, int* __restrict__ csr_src,
                                 float* __restrict__ csr_w, int e) {
  int i = blockIdx.x * TPB + threadIdx.x;
  if (i >= e) return;
  int s = src[i], d = dst[i];
  int p = atomicAdd(&fill[d], 1);
  int pos = rowptr[d] + p;
  csr_src[pos] = s;
  csr_w[pos] = dinv[s] * dinv[d];
}

// ------- gather aggregation, fused finalize: out = relu(sum_in + h*dinv^2 + b) -------
template <int OD>
__global__ __launch_bounds__(256) void gather_kernel(
    const float* __restrict__ hlin, const int* __restrict__ rowptr,
    const int* __restrict__ csr_src, const float* __restrict__ csr_w,
    const float* __restrict__ dinv, const float* __restrict__ b,
    float* __restrict__ out, int n) {
  constexpr int Q  = OD / 4;
  constexpr int NS = TPB / Q;
  const int tid = threadIdx.x;
  const int tx = tid & (Q - 1), slot = tid / Q;
  int node = blockIdx.x * NS + slot;
  if (node >= n) return;
  const float4* h4 = (const float4*)hlin;
  int start = rowptr[node], end = rowptr[node + 1];
  float4 acc = make_float4(0, 0, 0, 0);
  int j = start;
  for (; j + 1 < end; j += 2) {
    int s0 = csr_src[j], s1 = csr_src[j + 1];
    float w0 = csr_w[j], w1 = csr_w[j + 1];
    float4 v0 = h4[(size_t)s0 * Q + tx];
    float4 v1 = h4[(size_t)s1 * Q + tx];
    acc.x += v0.x * w0 + v1.x * w1;
    acc.y += v0.y * w0 + v1.y * w1;
    acc.z += v0.z * w0 + v1.z * w1;
    acc.w += v0.w * w0 + v1.w * w1;
  }
  if (j < end) {
    int s0 = csr_src[j];
    float w0 = csr_w[j];
    float4 v0 = h4[(size_t)s0 * Q + tx];
    acc.x += v0.x * w0; acc.y += v0.y * w0; acc.z += v0.z * w0; acc.w += v0.w * w0;
  }
  float di = dinv[node];
  float sw = di * di;
  float4 hv = h4[(size_t)node * Q + tx];
  float4 bv = ((const float4*)b)[tx];
  acc.x = fmaxf(acc.x + hv.x * sw + bv.x, 0.f);
  acc.y = fmaxf(acc.y + hv.y * sw + bv.y, 0.f);
  acc.z = fmaxf(acc.z + hv.z * sw + bv.z, 0.f);
  acc.w = fmaxf(acc.w + hv.w * sw + bv.w, 0.f);
  ((float4*)out)[(size_t)node * Q + tx] = acc;
}

// ---------------- pool ----------------
__global__ void pool_kernel(const float* __restrict__ h, const int* __restrict__ batch,
                            float* __restrict__ gsum, float* __restrict__ gcnt, int n) {
  int i = blockIdx.x * TPB + threadIdx.x;
  if (i >= n * 16) return;
  int node = i >> 4, q = i & 15;
  int g = batch[node];
  float4 v = ((const float4*)h)[i];
  float* p = gsum + (size_t)g * LAT + q * 4;
  atomicAdd(p + 0, v.x); atomicAdd(p + 1, v.y);
  atomicAdd(p + 2, v.z); atomicAdd(p + 3, v.w);
  if (q == 0) atomicAdd(&gcnt[g], 1.f);
}

__global__ void div_kernel(const float* __restrict__ gsum, const float* __restrict__ gcnt,
                           float* __restrict__ out, int total) {
  int i = blockIdx.x * TPB + threadIdx.x;
  if (i < total) out[i] = gsum[i] / fmaxf(gcnt[i >> 6], 1.f);
}

extern "C" void kernel_launch(void* const* d_in, const int* in_sizes, int n_in,
                              void* d_out, int out_size, void* d_ws, size_t ws_size,
                              hipStream_t stream) {
  const float* x     = (const float*)d_in[0];
  const float* W_emb = (const float*)d_in[1];
  const float* b_emb = (const float*)d_in[2];
  const float* W1    = (const float*)d_in[3];
  const float* b1    = (const float*)d_in[4];
  const float* W2    = (const float*)d_in[5];
  const float* b2    = (const float*)d_in[6];
  const int*   ei    = (const int*)d_in[7];
  const int*   batch = (const int*)d_in[8];
  const int n = in_sizes[8];
  const int e = in_sizes[7] / 2;
  const int* srcp = ei;
  const int* dstp = ei + e;
  float* out = (float*)d_out;

  char* ws = (char*)d_ws;
  size_t off = 0;
  auto alloc = [&](size_t bytes) {
    void* p = ws + off;
    off += (bytes + 255) & ~(size_t)255;
    return p;
  };
  float* bufA    = (float*)alloc((size_t)n * HID * 4);
  float* bufB    = (float*)alloc((size_t)n * HID * 4);
  float* dinv    = (float*)alloc((size_t)n * 4);
  int*   cnt     = (int*)alloc((size_t)n * 4);
  int*   fill    = (int*)alloc((size_t)n * 4);
  int*   rowptr  = (int*)alloc((size_t)(n + 1) * 4);
  int*   bsum    = (int*)alloc((size_t)512 * 4);
  int*   csr_src = (int*)alloc((size_t)e * 4);
  float* csr_w   = (float*)alloc((size_t)e * 4);
  float* gsum    = (float*)alloc((size_t)GG * LAT * 4);
  float* gcnt    = (float*)alloc((size_t)GG * 4);

  const int nb = (n + TPB - 1) / TPB;

  hipMemsetAsync(cnt, 0, (size_t)n * 4, stream);
  hipMemsetAsync(fill, 0, (size_t)n * 4, stream);
  hipMemsetAsync(gsum, 0, (size_t)GG * LAT * 4, stream);
  hipMemsetAsync(gcnt, 0, (size_t)GG * 4, stream);

  // h0 = relu(x @ W_emb + b_emb) -> bufA
  embed_kernel<<<2048, TPB, 0, stream>>>(x, W_emb, b_emb, bufA, n);

  // CSR by dst + dinv
  deg_count_kernel<<<(e + TPB - 1) / TPB, TPB, 0, stream>>>(dstp, cnt, e);
  dinv_kernel<<<nb, TPB, 0, stream>>>(cnt, dinv, n);
  scan1_kernel<<<nb, TPB, 0, stream>>>(cnt, rowptr, bsum, n);
  scan2_kernel<<<1, 512, 0, stream>>>(bsum, nb);
  scan3_kernel<<<nb, TPB, 0, stream>>>(rowptr, bsum, n, e);
  build_csr_kernel<<<(e + TPB - 1) / TPB, TPB, 0, stream>>>(
      srcp, dstp, rowptr, fill, dinv, csr_src, csr_w, e);

  // conv1: lin -> bufB; gather(+self+bias+relu) -> bufA
  lin_kernel<HID><<<2048, TPB, 0, stream>>>(bufA, W1, bufB, n);
  gather_kernel<HID><<<(n * (HID / 4) + TPB - 1) / TPB, TPB, 0, stream>>>(
      bufB, rowptr, csr_src, csr_w, dinv, b1, bufA, n);

  // conv2: lin -> bufB (n x 64); gather -> bufA (n x 64)
  lin_kernel<LAT><<<2048, TPB, 0, stream>>>(bufA, W2, bufB, n);
  gather_kernel<LAT><<<(n * (LAT / 4) + TPB - 1) / TPB, TPB, 0, stream>>>(
      bufB, rowptr, csr_src, csr_w, dinv, b2, bufA, n);

  // mean pool
  pool_kernel<<<(n * 16 + TPB - 1) / TPB, TPB, 0, stream>>>(bufA, batch, gsum, gcnt, n);
  div_kernel<<<(GG * LAT + TPB - 1) / TPB, TPB, 0, stream>>>(gsum, gcnt, out, GG * LAT);
}

// Round 3
// 507.103 us; speedup vs baseline: 8.9255x; 1.3917x over previous
//
#include <hip/hip_runtime.h>

#define TPB 256
constexpr int DIN = 47;
constexpr int HID = 128;
constexpr int LAT = 64;
constexpr int GG  = 1024;

// ---------------- embed: out = relu(x @ W_emb + b), x:[n,47] W:[47,128] ----------------
__global__ __launch_bounds__(256) void embed_kernel(
    const float* __restrict__ x, const float* __restrict__ W,
    const float* __restrict__ b, float* __restrict__ out, int n) {
  __shared__ float Wl[DIN * HID];
  __shared__ float bl[HID];
  __shared__ float xs[8][48];
  const int tid = threadIdx.x;
  for (int i = tid; i < DIN * HID; i += TPB) Wl[i] = W[i];
  if (tid < HID) bl[tid] = b[tid];
  const int tx = tid & 31, slot = tid >> 5;
  const float4* Wl4 = (const float4*)Wl;
  for (int base = blockIdx.x * 8; base < n; base += gridDim.x * 8) {
    __syncthreads();
    for (int i = tid; i < 8 * DIN; i += TPB) {
      int s = i / DIN, k = i - s * DIN;
      int node = base + s;
      xs[s][k] = (node < n) ? x[node * DIN + k] : 0.f;
    }
    __syncthreads();
    int node = base + slot;
    if (node < n) {
      float4 acc = ((const float4*)bl)[tx];
      #pragma unroll
      for (int k = 0; k < DIN; ++k) {
        float xv = xs[slot][k];
        float4 w = Wl4[k * 32 + tx];
        acc.x += xv * w.x; acc.y += xv * w.y; acc.z += xv * w.z; acc.w += xv * w.w;
      }
      acc.x = fmaxf(acc.x, 0.f); acc.y = fmaxf(acc.y, 0.f);
      acc.z = fmaxf(acc.z, 0.f); acc.w = fmaxf(acc.w, 0.f);
      ((float4*)out)[node * 32 + tx] = acc;
    }
  }
}

// ---------------- lin: out[n,OD] = h[n,128] @ W[128,OD] (no bias) ----------------
template <int OD>
__global__ __launch_bounds__(256) void lin_kernel(
    const float* __restrict__ h, const float* __restrict__ W,
    float* __restrict__ out, int n) {
  constexpr int Q  = OD / 4;
  constexpr int NS = TPB / Q;
  __shared__ float Wl[HID * OD];
  __shared__ float xs[NS][HID];
  const int tid = threadIdx.x;
  for (int i = tid; i < HID * OD; i += TPB) Wl[i] = W[i];
  const int tx = tid & (Q - 1), slot = tid / Q;
  const float4* Wl4 = (const float4*)Wl;
  const float4* h4  = (const float4*)h;
  for (int base = blockIdx.x * NS; base < n; base += gridDim.x * NS) {
    __syncthreads();
    for (int i = tid; i < NS * 32; i += TPB) {
      int s = i >> 5, q = i & 31;
      int node = base + s;
      ((float4*)xs)[i] = (node < n) ? h4[(size_t)node * 32 + q] : make_float4(0, 0, 0, 0);
    }
    __syncthreads();
    int node = base + slot;
    if (node < n) {
      float4 acc = make_float4(0, 0, 0, 0);
      #pragma unroll 8
      for (int k = 0; k < HID; ++k) {
        float xv = xs[slot][k];
        float4 w = Wl4[k * Q + tx];
        acc.x += xv * w.x; acc.y += xv * w.y; acc.z += xv * w.z; acc.w += xv * w.w;
      }
      ((float4*)out)[(size_t)node * Q + tx] = acc;
    }
  }
}

// ---------------- CSR build ----------------
__global__ void deg_count_kernel(const int* __restrict__ dst, int* __restrict__ cnt, int e) {
  int i = blockIdx.x * TPB + threadIdx.x;
  if (i < e) atomicAdd(&cnt[dst[i]], 1);
}

__global__ void dinv_kernel(const int* __restrict__ cnt, float* __restrict__ dinv, int n) {
  int i = blockIdx.x * TPB + threadIdx.x;
  if (i < n) dinv[i] = rsqrtf((float)cnt[i] + 1.f);
}

// block-local exclusive scan; block totals to bsum
__global__ void scan1_kernel(const int* __restrict__ cnt, int* __restrict__ rowptr,
                             int* __restrict__ bsum, int n) {
  __shared__ int sh[TPB];
  int i = blockIdx.x * TPB + threadIdx.x;
  int v = (i < n) ? cnt[i] : 0;
  sh[threadIdx.x] = v;
  __syncthreads();
  for (int off = 1; off < TPB; off <<= 1) {
    int t = (threadIdx.x >= off) ? sh[threadIdx.x - off] : 0;
    __syncthreads();
    sh[threadIdx.x] += t;
    __syncthreads();
  }
  if (i < n) rowptr[i] = sh[threadIdx.x] - v;      // exclusive within block
  if (threadIdx.x == TPB - 1) bsum[blockIdx.x] = sh[threadIdx.x];
}

// single-block scan of block totals
__global__ void scan2_kernel(int* __restrict__ bsum, int nb) {
  __shared__ int sh[512];
  __shared__ int carry;
  if (threadIdx.x == 0) carry = 0;
  __syncthreads();
  for (int base = 0; base < nb; base += 512) {
    int i = base + threadIdx.x;
    int v = (i < nb) ? bsum[i] : 0;
    sh[threadIdx.x] = v;
    __syncthreads();
    for (int off = 1; off < 512; off <<= 1) {
      int t = (threadIdx.x >= off) ? sh[threadIdx.x - off] : 0;
      __syncthreads();
      sh[threadIdx.x] += t;
      __syncthreads();
    }
    if (i < nb) bsum[i] = carry + sh[threadIdx.x] - v;  // exclusive
    __syncthreads();
    if (threadIdx.x == 0) carry += sh[511];
    __syncthreads();
  }
}

__global__ void scan3_kernel(int* __restrict__ rowptr, const int* __restrict__ bsum,
                             int n, int e) {
  int i = blockIdx.x * TPB + threadIdx.x;
  if (i < n) rowptr[i] += bsum[blockIdx.x];
  if (i == 0) rowptr[n] = e;
}

__global__ void build_csr_kernel(const int* __restrict__ src, const int* __restrict__ dst,
                                 const int* __restrict__ rowptr, int* __restrict__ fill,
                                 const float* __restrict__ dinv, int* __restrict__ csr_src,
                                 float* __restrict__ csr_w, int e) {
  int i = blockIdx.x * TPB + threadIdx.x;
  if (i >= e) return;
  int s = src[i], d = dst[i];
  int p = atomicAdd(&fill[d], 1);
  int pos = rowptr[d] + p;
  csr_src[pos] = s;
  csr_w[pos] = dinv[s] * dinv[d];
}

// ------- gather aggregation, fused finalize: out = relu(sum_in + h*dinv^2 + b) -------
template <int OD>
__global__ __launch_bounds__(256) void gather_kernel(
    const float* __restrict__ hlin, const int* __restrict__ rowptr,
    const int* __restrict__ csr_src, const float* __restrict__ csr_w,
    const float* __restrict__ dinv, const float* __restrict__ b,
    float* __restrict__ out, int n) {
  constexpr int Q  = OD / 4;
  constexpr int NS = TPB / Q;
  const int tid = threadIdx.x;
  const int tx = tid & (Q - 1), slot = tid / Q;
  int node = blockIdx.x * NS + slot;
  if (node >= n) return;
  const float4* h4 = (const float4*)hlin;
  int start = rowptr[node], end = rowptr[node + 1];
  float4 acc = make_float4(0, 0, 0, 0);
  int j = start;
  for (; j + 1 < end; j += 2) {
    int s0 = csr_src[j], s1 = csr_src[j + 1];
    float w0 = csr_w[j], w1 = csr_w[j + 1];
    float4 v0 = h4[(size_t)s0 * Q + tx];
    float4 v1 = h4[(size_t)s1 * Q + tx];
    acc.x += v0.x * w0 + v1.x * w1;
    acc.y += v0.y * w0 + v1.y * w1;
    acc.z += v0.z * w0 + v1.z * w1;
    acc.w += v0.w * w0 + v1.w * w1;
  }
  if (j < end) {
    int s0 = csr_src[j];
    float w0 = csr_w[j];
    float4 v0 = h4[(size_t)s0 * Q + tx];
    acc.x += v0.x * w0; acc.y += v0.y * w0; acc.z += v0.z * w0; acc.w += v0.w * w0;
  }
  float di = dinv[node];
  float sw = di * di;
  float4 hv = h4[(size_t)node * Q + tx];
  float4 bv = ((const float4*)b)[tx];
  acc.x = fmaxf(acc.x + hv.x * sw + bv.x, 0.f);
  acc.y = fmaxf(acc.y + hv.y * sw + bv.y, 0.f);
  acc.z = fmaxf(acc.z + hv.z * sw + bv.z, 0.f);
  acc.w = fmaxf(acc.w + hv.w * sw + bv.w, 0.f);
  ((float4*)out)[(size_t)node * Q + tx] = acc;
}

// ---------------- pool: batch is SORTED -> segment mean, no atomics ----------------
__global__ void gstart_kernel(const int* __restrict__ batch, int* __restrict__ gstart,
                              int n, int G) {
  int i = blockIdx.x * TPB + threadIdx.x;
  if (i >= n) return;
  int bi = batch[i];
  int bp = (i == 0) ? -1 : batch[i - 1];
  for (int g = bp + 1; g <= bi; ++g) gstart[g] = i;
  if (i == n - 1)
    for (int g = bi + 1; g <= G; ++g) gstart[g] = n;
}

__global__ __launch_bounds__(256) void pool2_kernel(
    const float* __restrict__ h, const int* __restrict__ gstart,
    float* __restrict__ out) {
  __shared__ float sh[4][LAT];
  int g = blockIdx.x;
  int s = gstart[g], epos = gstart[g + 1];
  int c = threadIdx.x & (LAT - 1), r = threadIdx.x >> 6;
  float acc = 0.f;
  for (int i = s + r; i < epos; i += 4)
    acc += h[(size_t)i * LAT + c];
  sh[r][c] = acc;
  __syncthreads();
  if (r == 0) {
    float v = sh[0][c] + sh[1][c] + sh[2][c] + sh[3][c];
    out[(size_t)g * LAT + c] = v / fmaxf((float)(epos - s), 1.f);
  }
}

extern "C" void kernel_launch(void* const* d_in, const int* in_sizes, int n_in,
                              void* d_out, int out_size, void* d_ws, size_t ws_size,
                              hipStream_t stream) {
  const float* x     = (const float*)d_in[0];
  const float* W_emb = (const float*)d_in[1];
  const float* b_emb = (const float*)d_in[2];
  const float* W1    = (const float*)d_in[3];
  const float* b1    = (const float*)d_in[4];
  const float* W2    = (const float*)d_in[5];
  const float* b2    = (const float*)d_in[6];
  const int*   ei    = (const int*)d_in[7];
  const int*   batch = (const int*)d_in[8];
  const int n = in_sizes[8];
  const int e = in_sizes[7] / 2;
  const int* srcp = ei;
  const int* dstp = ei + e;
  float* out = (float*)d_out;

  char* ws = (char*)d_ws;
  size_t off = 0;
  auto alloc = [&](size_t bytes) {
    void* p = ws + off;
    off += (bytes + 255) & ~(size_t)255;
    return p;
  };
  float* bufA    = (float*)alloc((size_t)n * HID * 4);
  float* bufB    = (float*)alloc((size_t)n * HID * 4);
  float* dinv    = (float*)alloc((size_t)n * 4);
  int*   cnt     = (int*)alloc((size_t)n * 4);
  int*   fill    = (int*)alloc((size_t)n * 4);
  int*   rowptr  = (int*)alloc((size_t)(n + 1) * 4);
  int*   bsum    = (int*)alloc((size_t)512 * 4);
  int*   csr_src = (int*)alloc((size_t)e * 4);
  float* csr_w   = (float*)alloc((size_t)e * 4);
  int*   gstart  = (int*)alloc((size_t)(GG + 1) * 4);

  const int nb = (n + TPB - 1) / TPB;

  hipMemsetAsync(cnt, 0, (size_t)n * 4, stream);
  hipMemsetAsync(fill, 0, (size_t)n * 4, stream);

  // h0 = relu(x @ W_emb + b_emb) -> bufA
  embed_kernel<<<2048, TPB, 0, stream>>>(x, W_emb, b_emb, bufA, n);

  // CSR by dst + dinv
  deg_count_kernel<<<(e + TPB - 1) / TPB, TPB, 0, stream>>>(dstp, cnt, e);
  dinv_kernel<<<nb, TPB, 0, stream>>>(cnt, dinv, n);
  scan1_kernel<<<nb, TPB, 0, stream>>>(cnt, rowptr, bsum, n);
  scan2_kernel<<<1, 512, 0, stream>>>(bsum, nb);
  scan3_kernel<<<nb, TPB, 0, stream>>>(rowptr, bsum, n, e);
  build_csr_kernel<<<(e + TPB - 1) / TPB, TPB, 0, stream>>>(
      srcp, dstp, rowptr, fill, dinv, csr_src, csr_w, e);

  // graph segment starts (batch sorted)
  gstart_kernel<<<nb, TPB, 0, stream>>>(batch, gstart, n, GG);

  // conv1: lin -> bufB; gather(+self+bias+relu) -> bufA
  lin_kernel<HID><<<2048, TPB, 0, stream>>>(bufA, W1, bufB, n);
  gather_kernel<HID><<<(n * (HID / 4) + TPB - 1) / TPB, TPB, 0, stream>>>(
      bufB, rowptr, csr_src, csr_w, dinv, b1, bufA, n);

  // conv2: lin -> bufB (n x 64); gather -> bufA (n x 64)
  lin_kernel<LAT><<<2048, TPB, 0, stream>>>(bufA, W2, bufB, n);
  gather_kernel<LAT><<<(n * (LAT / 4) + TPB - 1) / TPB, TPB, 0, stream>>>(
      bufB, rowptr, csr_src, csr_w, dinv, b2, bufA, n);

  // mean pool (segment-based, no atomics)
  pool2_kernel<<<GG, TPB, 0, stream>>>(bufA, gstart, out);
}

// Round 4
// 434.824 us; speedup vs baseline: 10.4092x; 1.1662x over previous
//
#include <hip/hip_runtime.h>

#define TPB 256
constexpr int DIN = 47;
constexpr int HID = 128;
constexpr int LAT = 64;
constexpr int GG  = 1024;

__device__ inline ushort f2bf(float f) {          // round-to-nearest-even bf16
  uint32_t u = __float_as_uint(f);
  return (ushort)((u + 0x7FFFu + ((u >> 16) & 1u)) >> 16);
}
__device__ inline float bf2f(ushort s) {
  return __uint_as_float(((uint32_t)s) << 16);
}

// ---------------- embed: out = relu(x @ W_emb + b), x:[n,47] W:[47,128] ----------------
__global__ __launch_bounds__(256) void embed_kernel(
    const float* __restrict__ x, const float* __restrict__ W,
    const float* __restrict__ b, float* __restrict__ out, int n) {
  __shared__ float Wl[DIN * HID];
  __shared__ float bl[HID];
  __shared__ float xs[8][48];
  const int tid = threadIdx.x;
  for (int i = tid; i < DIN * HID; i += TPB) Wl[i] = W[i];
  if (tid < HID) bl[tid] = b[tid];
  const int tx = tid & 31, slot = tid >> 5;
  const float4* Wl4 = (const float4*)Wl;
  for (int base = blockIdx.x * 8; base < n; base += gridDim.x * 8) {
    __syncthreads();
    for (int i = tid; i < 8 * DIN; i += TPB) {
      int s = i / DIN, k = i - s * DIN;
      int node = base + s;
      xs[s][k] = (node < n) ? x[node * DIN + k] : 0.f;
    }
    __syncthreads();
    int node = base + slot;
    if (node < n) {
      float4 acc = ((const float4*)bl)[tx];
      #pragma unroll
      for (int k = 0; k < DIN; ++k) {
        float xv = xs[slot][k];
        float4 w = Wl4[k * 32 + tx];
        acc.x += xv * w.x; acc.y += xv * w.y; acc.z += xv * w.z; acc.w += xv * w.w;
      }
      acc.x = fmaxf(acc.x, 0.f); acc.y = fmaxf(acc.y, 0.f);
      acc.z = fmaxf(acc.z, 0.f); acc.w = fmaxf(acc.w, 0.f);
      ((float4*)out)[node * 32 + tx] = acc;
    }
  }
}

// ------- lin: out[n,OD] (bf16) = h[n,128] (fp32) @ W[128,OD], no bias -------
template <int OD>
__global__ __launch_bounds__(256) void lin_kernel(
    const float* __restrict__ h, const float* __restrict__ W,
    ushort* __restrict__ out, int n) {
  constexpr int Q  = OD / 4;
  constexpr int NS = TPB / Q;
  __shared__ float Wl[HID * OD];
  __shared__ float xs[NS][HID];
  const int tid = threadIdx.x;
  for (int i = tid; i < HID * OD; i += TPB) Wl[i] = W[i];
  const int tx = tid & (Q - 1), slot = tid / Q;
  const float4* Wl4 = (const float4*)Wl;
  const float4* h4  = (const float4*)h;
  for (int base = blockIdx.x * NS; base < n; base += gridDim.x * NS) {
    __syncthreads();
    for (int i = tid; i < NS * 32; i += TPB) {
      int s = i >> 5, q = i & 31;
      int node = base + s;
      ((float4*)xs)[i] = (node < n) ? h4[(size_t)node * 32 + q] : make_float4(0, 0, 0, 0);
    }
    __syncthreads();
    int node = base + slot;
    if (node < n) {
      float4 acc = make_float4(0, 0, 0, 0);
      #pragma unroll 8
      for (int k = 0; k < HID; ++k) {
        float xv = xs[slot][k];
        float4 w = Wl4[k * Q + tx];
        acc.x += xv * w.x; acc.y += xv * w.y; acc.z += xv * w.z; acc.w += xv * w.w;
      }
      ushort4 o;
      o.x = f2bf(acc.x); o.y = f2bf(acc.y); o.z = f2bf(acc.z); o.w = f2bf(acc.w);
      ((ushort4*)out)[(size_t)node * Q + tx] = o;
    }
  }
}

// ---------------- CSR build ----------------
__global__ void deg_count_kernel(const int* __restrict__ dst, int* __restrict__ cnt, int e) {
  int i = blockIdx.x * TPB + threadIdx.x;
  if (i < e) atomicAdd(&cnt[dst[i]], 1);
}

__global__ void dinv_kernel(const int* __restrict__ cnt, float* __restrict__ dinv, int n) {
  int i = blockIdx.x * TPB + threadIdx.x;
  if (i < n) dinv[i] = rsqrtf((float)cnt[i] + 1.f);
}

__global__ void scan1_kernel(const int* __restrict__ cnt, int* __restrict__ rowptr,
                             int* __restrict__ bsum, int n) {
  __shared__ int sh[TPB];
  int i = blockIdx.x * TPB + threadIdx.x;
  int v = (i < n) ? cnt[i] : 0;
  sh[threadIdx.x] = v;
  __syncthreads();
  for (int off = 1; off < TPB; off <<= 1) {
    int t = (threadIdx.x >= off) ? sh[threadIdx.x - off] : 0;
    __syncthreads();
    sh[threadIdx.x] += t;
    __syncthreads();
  }
  if (i < n) rowptr[i] = sh[threadIdx.x] - v;
  if (threadIdx.x == TPB - 1) bsum[blockIdx.x] = sh[threadIdx.x];
}

__global__ void scan2_kernel(int* __restrict__ bsum, int nb) {
  __shared__ int sh[512];
  __shared__ int carry;
  if (threadIdx.x == 0) carry = 0;
  __syncthreads();
  for (int base = 0; base < nb; base += 512) {
    int i = base + threadIdx.x;
    int v = (i < nb) ? bsum[i] : 0;
    sh[threadIdx.x] = v;
    __syncthreads();
    for (int off = 1; off < 512; off <<= 1) {
      int t = (threadIdx.x >= off) ? sh[threadIdx.x - off] : 0;
      __syncthreads();
      sh[threadIdx.x] += t;
      __syncthreads();
    }
    if (i < nb) bsum[i] = carry + sh[threadIdx.x] - v;
    __syncthreads();
    if (threadIdx.x == 0) carry += sh[511];
    __syncthreads();
  }
}

__global__ void scan3_kernel(int* __restrict__ rowptr, const int* __restrict__ bsum,
                             int n, int e) {
  int i = blockIdx.x * TPB + threadIdx.x;
  if (i < n) rowptr[i] += bsum[blockIdx.x];
  if (i == 0) rowptr[n] = e;
}

__global__ void build_csr_kernel(const int* __restrict__ src, const int* __restrict__ dst,
                                 const int* __restrict__ rowptr, int* __restrict__ fill,
                                 const float* __restrict__ dinv, int* __restrict__ csr_src,
                                 float* __restrict__ csr_w, int e) {
  int i = blockIdx.x * TPB + threadIdx.x;
  if (i >= e) return;
  int s = src[i], d = dst[i];
  int p = atomicAdd(&fill[d], 1);
  int pos = rowptr[d] + p;
  csr_src[pos] = s;
  csr_w[pos] = dinv[s] * dinv[d];
}

// --- gather over bf16 rows + fused finalize: out = relu(sum + h*dinv^2 + b), fp32 out ---
template <int OD>
__global__ __launch_bounds__(256) void gather_kernel(
    const ushort* __restrict__ hlin, const int* __restrict__ rowptr,
    const int* __restrict__ csr_src, const float* __restrict__ csr_w,
    const float* __restrict__ dinv, const float* __restrict__ b,
    float* __restrict__ out, int n) {
  constexpr int Q  = OD / 4;
  constexpr int NS = TPB / Q;
  const int tid = threadIdx.x;
  const int tx = tid & (Q - 1), slot = tid / Q;
  int node = blockIdx.x * NS + slot;
  if (node >= n) return;
  const ushort4* h4 = (const ushort4*)hlin;
  int start = rowptr[node], end = rowptr[node + 1];
  float ax = 0.f, ay = 0.f, az = 0.f, aw = 0.f;
  int j = start;
  for (; j + 3 < end; j += 4) {
    int s0 = csr_src[j], s1 = csr_src[j + 1], s2 = csr_src[j + 2], s3 = csr_src[j + 3];
    float w0 = csr_w[j], w1 = csr_w[j + 1], w2 = csr_w[j + 2], w3 = csr_w[j + 3];
    ushort4 v0 = h4[(size_t)s0 * Q + tx];
    ushort4 v1 = h4[(size_t)s1 * Q + tx];
    ushort4 v2 = h4[(size_t)s2 * Q + tx];
    ushort4 v3 = h4[(size_t)s3 * Q + tx];
    ax += bf2f(v0.x) * w0 + bf2f(v1.x) * w1 + bf2f(v2.x) * w2 + bf2f(v3.x) * w3;
    ay += bf2f(v0.y) * w0 + bf2f(v1.y) * w1 + bf2f(v2.y) * w2 + bf2f(v3.y) * w3;
    az += bf2f(v0.z) * w0 + bf2f(v1.z) * w1 + bf2f(v2.z) * w2 + bf2f(v3.z) * w3;
    aw += bf2f(v0.w) * w0 + bf2f(v1.w) * w1 + bf2f(v2.w) * w2 + bf2f(v3.w) * w3;
  }
  for (; j < end; ++j) {
    int s0 = csr_src[j];
    float w0 = csr_w[j];
    ushort4 v0 = h4[(size_t)s0 * Q + tx];
    ax += bf2f(v0.x) * w0; ay += bf2f(v0.y) * w0;
    az += bf2f(v0.z) * w0; aw += bf2f(v0.w) * w0;
  }
  float di = dinv[node];
  float sw = di * di;
  ushort4 hv = h4[(size_t)node * Q + tx];
  float4 bv = ((const float4*)b)[tx];
  float4 o;
  o.x = fmaxf(ax + bf2f(hv.x) * sw + bv.x, 0.f);
  o.y = fmaxf(ay + bf2f(hv.y) * sw + bv.y, 0.f);
  o.z = fmaxf(az + bf2f(hv.z) * sw + bv.z, 0.f);
  o.w = fmaxf(aw + bf2f(hv.w) * sw + bv.w, 0.f);
  ((float4*)out)[(size_t)node * Q + tx] = o;
}

// ---------------- pool: batch sorted -> segment mean ----------------
__global__ void gstart_kernel(const int* __restrict__ batch, int* __restrict__ gstart,
                              int n, int G) {
  int i = blockIdx.x * TPB + threadIdx.x;
  if (i >= n) return;
  int bi = batch[i];
  int bp = (i == 0) ? -1 : batch[i - 1];
  for (int g = bp + 1; g <= bi; ++g) gstart[g] = i;
  if (i == n - 1)
    for (int g = bi + 1; g <= G; ++g) gstart[g] = n;
}

__global__ __launch_bounds__(256) void pool2_kernel(
    const float* __restrict__ h, const int* __restrict__ gstart,
    float* __restrict__ out) {
  __shared__ float sh[4][LAT];
  int g = blockIdx.x;
  int s = gstart[g], epos = gstart[g + 1];
  int c = threadIdx.x & (LAT - 1), r = threadIdx.x >> 6;
  float acc = 0.f;
  for (int i = s + r; i < epos; i += 4)
    acc += h[(size_t)i * LAT + c];
  sh[r][c] = acc;
  __syncthreads();
  if (r == 0) {
    float v = sh[0][c] + sh[1][c] + sh[2][c] + sh[3][c];
    out[(size_t)g * LAT + c] = v / fmaxf((float)(epos - s), 1.f);
  }
}

extern "C" void kernel_launch(void* const* d_in, const int* in_sizes, int n_in,
                              void* d_out, int out_size, void* d_ws, size_t ws_size,
                              hipStream_t stream) {
  const float* x     = (const float*)d_in[0];
  const float* W_emb = (const float*)d_in[1];
  const float* b_emb = (const float*)d_in[2];
  const float* W1    = (const float*)d_in[3];
  const float* b1    = (const float*)d_in[4];
  const float* W2    = (const float*)d_in[5];
  const float* b2    = (const float*)d_in[6];
  const int*   ei    = (const int*)d_in[7];
  const int*   batch = (const int*)d_in[8];
  const int n = in_sizes[8];
  const int e = in_sizes[7] / 2;
  const int* srcp = ei;
  const int* dstp = ei + e;
  float* out = (float*)d_out;

  char* ws = (char*)d_ws;
  size_t off = 0;
  auto alloc = [&](size_t bytes) {
    void* p = ws + off;
    off += (bytes + 255) & ~(size_t)255;
    return p;
  };
  float*  bufA    = (float*)alloc((size_t)n * HID * 4);    // h0 / h1 / h2 (fp32)
  ushort* bufB    = (ushort*)alloc((size_t)n * HID * 2);   // hlin (bf16)
  float*  dinv    = (float*)alloc((size_t)n * 4);
  int*    cnt     = (int*)alloc((size_t)n * 4);
  int*    fill    = (int*)alloc((size_t)n * 4);
  int*    rowptr  = (int*)alloc((size_t)(n + 1) * 4);
  int*    bsum    = (int*)alloc((size_t)512 * 4);
  int*    csr_src = (int*)alloc((size_t)e * 4);
  float*  csr_w   = (float*)alloc((size_t)e * 4);
  int*    gstart  = (int*)alloc((size_t)(GG + 1) * 4);

  const int nb = (n + TPB - 1) / TPB;

  hipMemsetAsync(cnt, 0, (size_t)n * 4, stream);
  hipMemsetAsync(fill, 0, (size_t)n * 4, stream);

  // h0 = relu(x @ W_emb + b_emb) -> bufA (fp32)
  embed_kernel<<<2048, TPB, 0, stream>>>(x, W_emb, b_emb, bufA, n);

  // CSR by dst + dinv
  deg_count_kernel<<<(e + TPB - 1) / TPB, TPB, 0, stream>>>(dstp, cnt, e);
  dinv_kernel<<<nb, TPB, 0, stream>>>(cnt, dinv, n);
  scan1_kernel<<<nb, TPB, 0, stream>>>(cnt, rowptr, bsum, n);
  scan2_kernel<<<1, 512, 0, stream>>>(bsum, nb);
  scan3_kernel<<<nb, TPB, 0, stream>>>(rowptr, bsum, n, e);
  build_csr_kernel<<<(e + TPB - 1) / TPB, TPB, 0, stream>>>(
      srcp, dstp, rowptr, fill, dinv, csr_src, csr_w, e);

  // graph segment starts (batch sorted)
  gstart_kernel<<<nb, TPB, 0, stream>>>(batch, gstart, n, GG);

  // conv1: lin(fp32->bf16) -> bufB; gather(bf16, +self+bias+relu) -> bufA (fp32)
  lin_kernel<HID><<<2048, TPB, 0, stream>>>(bufA, W1, bufB, n);
  gather_kernel<HID><<<(n * (HID / 4) + TPB - 1) / TPB, TPB, 0, stream>>>(
      bufB, rowptr, csr_src, csr_w, dinv, b1, bufA, n);

  // conv2: lin -> bufB (n x 64 bf16); gather -> bufA (n x 64 fp32)
  lin_kernel<LAT><<<2048, TPB, 0, stream>>>(bufA, W2, bufB, n);
  gather_kernel<LAT><<<(n * (LAT / 4) + TPB - 1) / TPB, TPB, 0, stream>>>(
      bufB, rowptr, csr_src, csr_w, dinv, b2, bufA, n);

  // mean pool
  pool2_kernel<<<GG, TPB, 0, stream>>>(bufA, gstart, out);
}

// Round 5
// 384.906 us; speedup vs baseline: 11.7591x; 1.1297x over previous
//
#include <hip/hip_runtime.h>

#define TPB 256
constexpr int DIN = 47;
constexpr int HID = 128;
constexpr int LAT = 64;
constexpr int GG  = 1024;

__device__ inline ushort f2bf(float f) {          // round-to-nearest-even bf16
  uint32_t u = __float_as_uint(f);
  return (ushort)((u + 0x7FFFu + ((u >> 16) & 1u)) >> 16);
}
__device__ inline float bf2f(ushort s) {
  return __uint_as_float(((uint32_t)s) << 16);
}

// ---------------- embed: out = relu(x @ W_emb + b), x:[n,47] W:[47,128] ----------------
__global__ __launch_bounds__(256) void embed_kernel(
    const float* __restrict__ x, const float* __restrict__ W,
    const float* __restrict__ b, float* __restrict__ out, int n) {
  __shared__ float Wl[DIN * HID];
  __shared__ float bl[HID];
  __shared__ float xs[8][48];
  const int tid = threadIdx.x;
  for (int i = tid; i < DIN * HID; i += TPB) Wl[i] = W[i];
  if (tid < HID) bl[tid] = b[tid];
  const int tx = tid & 31, slot = tid >> 5;
  const float4* Wl4 = (const float4*)Wl;
  for (int base = blockIdx.x * 8; base < n; base += gridDim.x * 8) {
    __syncthreads();
    for (int i = tid; i < 8 * DIN; i += TPB) {
      int s = i / DIN, k = i - s * DIN;
      int node = base + s;
      xs[s][k] = (node < n) ? x[node * DIN + k] : 0.f;
    }
    __syncthreads();
    int node = base + slot;
    if (node < n) {
      float4 acc = ((const float4*)bl)[tx];
      #pragma unroll
      for (int k = 0; k < DIN; ++k) {
        float xv = xs[slot][k];
        float4 w = Wl4[k * 32 + tx];
        acc.x += xv * w.x; acc.y += xv * w.y; acc.z += xv * w.z; acc.w += xv * w.w;
      }
      acc.x = fmaxf(acc.x, 0.f); acc.y = fmaxf(acc.y, 0.f);
      acc.z = fmaxf(acc.z, 0.f); acc.w = fmaxf(acc.w, 0.f);
      ((float4*)out)[node * 32 + tx] = acc;
    }
  }
}

// ------- lin: out[n,OD] (bf16) = h[n,128] (fp32) @ W[128,OD], no bias -------
template <int OD>
__global__ __launch_bounds__(256) void lin_kernel(
    const float* __restrict__ h, const float* __restrict__ W,
    ushort* __restrict__ out, int n) {
  constexpr int Q  = OD / 4;
  constexpr int NS = TPB / Q;
  __shared__ float Wl[HID * OD];
  __shared__ float xs[NS][HID];
  const int tid = threadIdx.x;
  for (int i = tid; i < HID * OD; i += TPB) Wl[i] = W[i];
  const int tx = tid & (Q - 1), slot = tid / Q;
  const float4* Wl4 = (const float4*)Wl;
  const float4* h4  = (const float4*)h;
  for (int base = blockIdx.x * NS; base < n; base += gridDim.x * NS) {
    __syncthreads();
    for (int i = tid; i < NS * 32; i += TPB) {
      int s = i >> 5, q = i & 31;
      int node = base + s;
      ((float4*)xs)[i] = (node < n) ? h4[(size_t)node * 32 + q] : make_float4(0, 0, 0, 0);
    }
    __syncthreads();
    int node = base + slot;
    if (node < n) {
      float4 acc = make_float4(0, 0, 0, 0);
      #pragma unroll 8
      for (int k = 0; k < HID; ++k) {
        float xv = xs[slot][k];
        float4 w = Wl4[k * Q + tx];
        acc.x += xv * w.x; acc.y += xv * w.y; acc.z += xv * w.z; acc.w += xv * w.w;
      }
      ushort4 o;
      o.x = f2bf(acc.x); o.y = f2bf(acc.y); o.z = f2bf(acc.z); o.w = f2bf(acc.w);
      ((ushort4*)out)[(size_t)node * Q + tx] = o;
    }
  }
}

// ---------------- CSR build ----------------
// pass 1: count degree AND record each edge's rank within its dst row
__global__ void deg_rank_kernel(const int* __restrict__ dst, int* __restrict__ cnt,
                                int* __restrict__ rank, int e) {
  int i = blockIdx.x * TPB + threadIdx.x;
  if (i < e) rank[i] = atomicAdd(&cnt[dst[i]], 1);
}

__global__ void dinv_kernel(const int* __restrict__ cnt, float* __restrict__ dinv, int n) {
  int i = blockIdx.x * TPB + threadIdx.x;
  if (i < n) dinv[i] = rsqrtf((float)cnt[i] + 1.f);
}

__global__ void scan1_kernel(const int* __restrict__ cnt, int* __restrict__ rowptr,
                             int* __restrict__ bsum, int n) {
  __shared__ int sh[TPB];
  int i = blockIdx.x * TPB + threadIdx.x;
  int v = (i < n) ? cnt[i] : 0;
  sh[threadIdx.x] = v;
  __syncthreads();
  for (int off = 1; off < TPB; off <<= 1) {
    int t = (threadIdx.x >= off) ? sh[threadIdx.x - off] : 0;
    __syncthreads();
    sh[threadIdx.x] += t;
    __syncthreads();
  }
  if (i < n) rowptr[i] = sh[threadIdx.x] - v;
  if (threadIdx.x == TPB - 1) bsum[blockIdx.x] = sh[threadIdx.x];
}

__global__ void scan2_kernel(int* __restrict__ bsum, int nb) {
  __shared__ int sh[512];
  __shared__ int carry;
  if (threadIdx.x == 0) carry = 0;
  __syncthreads();
  for (int base = 0; base < nb; base += 512) {
    int i = base + threadIdx.x;
    int v = (i < nb) ? bsum[i] : 0;
    sh[threadIdx.x] = v;
    __syncthreads();
    for (int off = 1; off < 512; off <<= 1) {
      int t = (threadIdx.x >= off) ? sh[threadIdx.x - off] : 0;
      __syncthreads();
      sh[threadIdx.x] += t;
      __syncthreads();
    }
    if (i < nb) bsum[i] = carry + sh[threadIdx.x] - v;
    __syncthreads();
    if (threadIdx.x == 0) carry += sh[511];
    __syncthreads();
  }
}

__global__ void scan3_kernel(int* __restrict__ rowptr, const int* __restrict__ bsum,
                             int n, int e) {
  int i = blockIdx.x * TPB + threadIdx.x;
  if (i < n) rowptr[i] += bsum[blockIdx.x];
  if (i == 0) rowptr[n] = e;
}

// pass 2: atomic-free placement, single 4B scattered write per edge
__global__ void place_kernel(const int* __restrict__ src, const int* __restrict__ dst,
                             const int* __restrict__ rowptr, const int* __restrict__ rank,
                             int* __restrict__ csr_src, int e) {
  int i = blockIdx.x * TPB + threadIdx.x;
  if (i >= e) return;
  csr_src[rowptr[dst[i]] + rank[i]] = src[i];
}

// --- gather over bf16 rows, w = dinv[s]*dinv[node] recomputed, fused finalize ---
template <int OD>
__global__ __launch_bounds__(256) void gather_kernel(
    const ushort* __restrict__ hlin, const int* __restrict__ rowptr,
    const int* __restrict__ csr_src, const float* __restrict__ dinv,
    const float* __restrict__ b, float* __restrict__ out, int n) {
  constexpr int Q  = OD / 4;
  constexpr int NS = TPB / Q;
  const int tid = threadIdx.x;
  const int tx = tid & (Q - 1), slot = tid / Q;
  int node = blockIdx.x * NS + slot;
  if (node >= n) return;
  const ushort4* h4 = (const ushort4*)hlin;
  int start = rowptr[node], end = rowptr[node + 1];
  float di = dinv[node];
  float ax = 0.f, ay = 0.f, az = 0.f, aw = 0.f;
  int j = start;
  for (; j + 3 < end; j += 4) {
    int s0 = csr_src[j], s1 = csr_src[j + 1], s2 = csr_src[j + 2], s3 = csr_src[j + 3];
    float w0 = dinv[s0] * di, w1 = dinv[s1] * di, w2 = dinv[s2] * di, w3 = dinv[s3] * di;
    ushort4 v0 = h4[(size_t)s0 * Q + tx];
    ushort4 v1 = h4[(size_t)s1 * Q + tx];
    ushort4 v2 = h4[(size_t)s2 * Q + tx];
    ushort4 v3 = h4[(size_t)s3 * Q + tx];
    ax += bf2f(v0.x) * w0 + bf2f(v1.x) * w1 + bf2f(v2.x) * w2 + bf2f(v3.x) * w3;
    ay += bf2f(v0.y) * w0 + bf2f(v1.y) * w1 + bf2f(v2.y) * w2 + bf2f(v3.y) * w3;
    az += bf2f(v0.z) * w0 + bf2f(v1.z) * w1 + bf2f(v2.z) * w2 + bf2f(v3.z) * w3;
    aw += bf2f(v0.w) * w0 + bf2f(v1.w) * w1 + bf2f(v2.w) * w2 + bf2f(v3.w) * w3;
  }
  for (; j < end; ++j) {
    int s0 = csr_src[j];
    float w0 = dinv[s0] * di;
    ushort4 v0 = h4[(size_t)s0 * Q + tx];
    ax += bf2f(v0.x) * w0; ay += bf2f(v0.y) * w0;
    az += bf2f(v0.z) * w0; aw += bf2f(v0.w) * w0;
  }
  float sw = di * di;
  ushort4 hv = h4[(size_t)node * Q + tx];
  float4 bv = ((const float4*)b)[tx];
  float4 o;
  o.x = fmaxf(ax + bf2f(hv.x) * sw + bv.x, 0.f);
  o.y = fmaxf(ay + bf2f(hv.y) * sw + bv.y, 0.f);
  o.z = fmaxf(az + bf2f(hv.z) * sw + bv.z, 0.f);
  o.w = fmaxf(aw + bf2f(hv.w) * sw + bv.w, 0.f);
  ((float4*)out)[(size_t)node * Q + tx] = o;
}

// ---------------- pool: batch sorted -> segment mean ----------------
__global__ void gstart_kernel(const int* __restrict__ batch, int* __restrict__ gstart,
                              int n, int G) {
  int i = blockIdx.x * TPB + threadIdx.x;
  if (i >= n) return;
  int bi = batch[i];
  int bp = (i == 0) ? -1 : batch[i - 1];
  for (int g = bp + 1; g <= bi; ++g) gstart[g] = i;
  if (i == n - 1)
    for (int g = bi + 1; g <= G; ++g) gstart[g] = n;
}

__global__ __launch_bounds__(256) void pool2_kernel(
    const float* __restrict__ h, const int* __restrict__ gstart,
    float* __restrict__ out) {
  __shared__ float sh[4][LAT];
  int g = blockIdx.x;
  int s = gstart[g], epos = gstart[g + 1];
  int c = threadIdx.x & (LAT - 1), r = threadIdx.x >> 6;
  float acc = 0.f;
  for (int i = s + r; i < epos; i += 4)
    acc += h[(size_t)i * LAT + c];
  sh[r][c] = acc;
  __syncthreads();
  if (r == 0) {
    float v = sh[0][c] + sh[1][c] + sh[2][c] + sh[3][c];
    out[(size_t)g * LAT + c] = v / fmaxf((float)(epos - s), 1.f);
  }
}

extern "C" void kernel_launch(void* const* d_in, const int* in_sizes, int n_in,
                              void* d_out, int out_size, void* d_ws, size_t ws_size,
                              hipStream_t stream) {
  const float* x     = (const float*)d_in[0];
  const float* W_emb = (const float*)d_in[1];
  const float* b_emb = (const float*)d_in[2];
  const float* W1    = (const float*)d_in[3];
  const float* b1    = (const float*)d_in[4];
  const float* W2    = (const float*)d_in[5];
  const float* b2    = (const float*)d_in[6];
  const int*   ei    = (const int*)d_in[7];
  const int*   batch = (const int*)d_in[8];
  const int n = in_sizes[8];
  const int e = in_sizes[7] / 2;
  const int* srcp = ei;
  const int* dstp = ei + e;
  float* out = (float*)d_out;

  char* ws = (char*)d_ws;
  size_t off = 0;
  auto alloc = [&](size_t bytes) {
    void* p = ws + off;
    off += (bytes + 255) & ~(size_t)255;
    return p;
  };
  float*  bufA    = (float*)alloc((size_t)n * HID * 4);    // h0 / h1 / h2 (fp32)
  ushort* bufB    = (ushort*)alloc((size_t)n * HID * 2);   // hlin (bf16)
  float*  dinv    = (float*)alloc((size_t)n * 4);
  int*    cnt     = (int*)alloc((size_t)n * 4);
  int*    rowptr  = (int*)alloc((size_t)(n + 1) * 4);
  int*    bsum    = (int*)alloc((size_t)512 * 4);
  int*    rank    = (int*)alloc((size_t)e * 4);
  int*    csr_src = (int*)alloc((size_t)e * 4);
  int*    gstart  = (int*)alloc((size_t)(GG + 1) * 4);

  const int nb = (n + TPB - 1) / TPB;
  const int eb = (e + TPB - 1) / TPB;

  hipMemsetAsync(cnt, 0, (size_t)n * 4, stream);

  // h0 = relu(x @ W_emb + b_emb) -> bufA (fp32)
  embed_kernel<<<2048, TPB, 0, stream>>>(x, W_emb, b_emb, bufA, n);

  // CSR by dst (counting sort, atomic-free placement) + dinv
  deg_rank_kernel<<<eb, TPB, 0, stream>>>(dstp, cnt, rank, e);
  dinv_kernel<<<nb, TPB, 0, stream>>>(cnt, dinv, n);
  scan1_kernel<<<nb, TPB, 0, stream>>>(cnt, rowptr, bsum, n);
  scan2_kernel<<<1, 512, 0, stream>>>(bsum, nb);
  scan3_kernel<<<nb, TPB, 0, stream>>>(rowptr, bsum, n, e);
  place_kernel<<<eb, TPB, 0, stream>>>(srcp, dstp, rowptr, rank, csr_src, e);

  // graph segment starts (batch sorted)
  gstart_kernel<<<nb, TPB, 0, stream>>>(batch, gstart, n, GG);

  // conv1: lin(fp32->bf16) -> bufB; gather(bf16, +self+bias+relu) -> bufA (fp32)
  lin_kernel<HID><<<2048, TPB, 0, stream>>>(bufA, W1, bufB, n);
  gather_kernel<HID><<<(n * (HID / 4) + TPB - 1) / TPB, TPB, 0, stream>>>(
      bufB, rowptr, csr_src, dinv, b1, bufA, n);

  // conv2: lin -> bufB (n x 64 bf16); gather -> bufA (n x 64 fp32)
  lin_kernel<LAT><<<2048, TPB, 0, stream>>>(bufA, W2, bufB, n);
  gather_kernel<LAT><<<(n * (LAT / 4) + TPB - 1) / TPB, TPB, 0, stream>>>(
      bufB, rowptr, csr_src, dinv, b2, bufA, n);

  // mean pool
  pool2_kernel<<<GG, TPB, 0, stream>>>(bufA, gstart, out);
}

// Round 6
// 295.943 us; speedup vs baseline: 15.2941x; 1.3006x over previous
//
#include <hip/hip_runtime.h>

#define TPB 256
constexpr int DIN = 47;
constexpr int HID = 128;
constexpr int LAT = 64;
constexpr int GG  = 1024;

typedef __attribute__((ext_vector_type(8))) short short8v;
typedef __attribute__((ext_vector_type(4))) float float4v;

__device__ inline ushort f2bf(float f) {          // round-to-nearest-even bf16
  uint32_t u = __float_as_uint(f);
  return (ushort)((u + 0x7FFFu + ((u >> 16) & 1u)) >> 16);
}
__device__ inline float bf2f(ushort s) {
  return __uint_as_float(((uint32_t)s) << 16);
}

// ---------------- embed: out(bf16) = relu(x @ W_emb + b), x:[n,47] fp32 ----------------
__global__ __launch_bounds__(256) void embed_kernel(
    const float* __restrict__ x, const float* __restrict__ W,
    const float* __restrict__ b, ushort* __restrict__ out, int n) {
  __shared__ float Wl[DIN * HID];
  __shared__ float bl[HID];
  __shared__ float xs[8][48];
  const int tid = threadIdx.x;
  for (int i = tid; i < DIN * HID; i += TPB) Wl[i] = W[i];
  if (tid < HID) bl[tid] = b[tid];
  const int tx = tid & 31, slot = tid >> 5;
  const float4* Wl4 = (const float4*)Wl;
  for (int base = blockIdx.x * 8; base < n; base += gridDim.x * 8) {
    __syncthreads();
    for (int i = tid; i < 8 * DIN; i += TPB) {
      int s = i / DIN, k = i - s * DIN;
      int node = base + s;
      xs[s][k] = (node < n) ? x[node * DIN + k] : 0.f;
    }
    __syncthreads();
    int node = base + slot;
    if (node < n) {
      float4 acc = ((const float4*)bl)[tx];
      #pragma unroll
      for (int k = 0; k < DIN; ++k) {
        float xv = xs[slot][k];
        float4 w = Wl4[k * 32 + tx];
        acc.x += xv * w.x; acc.y += xv * w.y; acc.z += xv * w.z; acc.w += xv * w.w;
      }
      ushort4 o;
      o.x = f2bf(fmaxf(acc.x, 0.f)); o.y = f2bf(fmaxf(acc.y, 0.f));
      o.z = f2bf(fmaxf(acc.z, 0.f)); o.w = f2bf(fmaxf(acc.w, 0.f));
      ((ushort4*)out)[node * 32 + tx] = o;
    }
  }
}

// ------- lin (MFMA): out[n,OD] bf16 = h[n,128] bf16 @ W[128,OD] fp32->bf16 -------
// A frag: row=lane&15, k=8*(lane>>4)+j (global loads, no LDS)
// B frag: col=lane&15, k=8*(lane>>4)+j  from LDS W^T, XOR-swizzled
// D frag: col=lane&15, row=4*(lane>>4)+r  [m89-verified]
template <int OD>
__global__ __launch_bounds__(256) void lin_mfma_kernel(
    const ushort* __restrict__ h, const float* __restrict__ W,
    ushort* __restrict__ out, int n) {
  __shared__ ushort Wt[OD * 128];   // [col][k] bf16, swizzled
  const int tid = threadIdx.x;
  for (int idx = tid; idx < 128 * OD; idx += TPB) {
    int k = idx / OD, c = idx - k * OD;      // W row-major read, coalesced
    Wt[c * 128 + (k ^ ((c & 7) << 3))] = f2bf(W[idx]);
  }
  __syncthreads();
  const int lane = tid & 63, wave = tid >> 6;
  const int rowA = lane & 15, kgrp = lane >> 4;
  const int nb0 = blockIdx.x * 64 + wave * 16;
  // load A fragments (16 nodes x 128 k per wave) straight from global
  int nodeA = nb0 + rowA; if (nodeA >= n) nodeA = n - 1;
  const ushort* hrow = h + (size_t)nodeA * 128 + kgrp * 8;
  short8v a0 = *(const short8v*)(hrow);
  short8v a1 = *(const short8v*)(hrow + 32);
  short8v a2 = *(const short8v*)(hrow + 64);
  short8v a3 = *(const short8v*)(hrow + 96);
  #pragma unroll
  for (int ct = 0; ct < OD / 16; ++ct) {
    const int c = ct * 16 + rowA;
    const int sw = (c & 7) << 3;
    const ushort* wc = &Wt[c * 128];
    float4v acc = {0.f, 0.f, 0.f, 0.f};
    acc = __builtin_amdgcn_mfma_f32_16x16x32_bf16(a0, *(const short8v*)(wc + ((kgrp * 8)       ^ sw)), acc, 0, 0, 0);
    acc = __builtin_amdgcn_mfma_f32_16x16x32_bf16(a1, *(const short8v*)(wc + ((kgrp * 8 + 32)  ^ sw)), acc, 0, 0, 0);
    acc = __builtin_amdgcn_mfma_f32_16x16x32_bf16(a2, *(const short8v*)(wc + ((kgrp * 8 + 64)  ^ sw)), acc, 0, 0, 0);
    acc = __builtin_amdgcn_mfma_f32_16x16x32_bf16(a3, *(const short8v*)(wc + ((kgrp * 8 + 96)  ^ sw)), acc, 0, 0, 0);
    #pragma unroll
    for (int r = 0; r < 4; ++r) {
      int node = nb0 + kgrp * 4 + r;
      if (node < n) out[(size_t)node * OD + c] = f2bf(acc[r]);
    }
  }
}

// ---------------- CSR build ----------------
__global__ void deg_rank_kernel(const int* __restrict__ dst, int* __restrict__ cnt,
                                int* __restrict__ rank, int e) {
  int i = blockIdx.x * TPB + threadIdx.x;
  if (i < e) rank[i] = atomicAdd(&cnt[dst[i]], 1);
}

__global__ void dinv_kernel(const int* __restrict__ cnt, float* __restrict__ dinv, int n) {
  int i = blockIdx.x * TPB + threadIdx.x;
  if (i < n) dinv[i] = rsqrtf((float)cnt[i] + 1.f);
}

__global__ void scan1_kernel(const int* __restrict__ cnt, int* __restrict__ rowptr,
                             int* __restrict__ bsum, int n) {
  __shared__ int sh[TPB];
  int i = blockIdx.x * TPB + threadIdx.x;
  int v = (i < n) ? cnt[i] : 0;
  sh[threadIdx.x] = v;
  __syncthreads();
  for (int off = 1; off < TPB; off <<= 1) {
    int t = (threadIdx.x >= off) ? sh[threadIdx.x - off] : 0;
    __syncthreads();
    sh[threadIdx.x] += t;
    __syncthreads();
  }
  if (i < n) rowptr[i] = sh[threadIdx.x] - v;
  if (threadIdx.x == TPB - 1) bsum[blockIdx.x] = sh[threadIdx.x];
}

__global__ void scan2_kernel(int* __restrict__ bsum, int nb) {
  __shared__ int sh[512];
  __shared__ int carry;
  if (threadIdx.x == 0) carry = 0;
  __syncthreads();
  for (int base = 0; base < nb; base += 512) {
    int i = base + threadIdx.x;
    int v = (i < nb) ? bsum[i] : 0;
    sh[threadIdx.x] = v;
    __syncthreads();
    for (int off = 1; off < 512; off <<= 1) {
      int t = (threadIdx.x >= off) ? sh[threadIdx.x - off] : 0;
      __syncthreads();
      sh[threadIdx.x] += t;
      __syncthreads();
    }
    if (i < nb) bsum[i] = carry + sh[threadIdx.x] - v;
    __syncthreads();
    if (threadIdx.x == 0) carry += sh[511];
    __syncthreads();
  }
}

__global__ void scan3_kernel(int* __restrict__ rowptr, const int* __restrict__ bsum,
                             int n, int e) {
  int i = blockIdx.x * TPB + threadIdx.x;
  if (i < n) rowptr[i] += bsum[blockIdx.x];
  if (i == 0) rowptr[n] = e;
}

__global__ void place_kernel(const int* __restrict__ src, const int* __restrict__ dst,
                             const int* __restrict__ rowptr, const int* __restrict__ rank,
                             int* __restrict__ csr_src, int e) {
  int i = blockIdx.x * TPB + threadIdx.x;
  if (i >= e) return;
  csr_src[rowptr[dst[i]] + rank[i]] = src[i];
}

// --- gather bf16 rows, w = dinv[s]*dinv[node], fused finalize, bf16 out ---
template <int OD>
__global__ __launch_bounds__(256) void gather_kernel(
    const ushort* __restrict__ hlin, const int* __restrict__ rowptr,
    const int* __restrict__ csr_src, const float* __restrict__ dinv,
    const float* __restrict__ b, ushort* __restrict__ out, int n) {
  constexpr int Q  = OD / 4;
  constexpr int NS = TPB / Q;
  const int tid = threadIdx.x;
  const int tx = tid & (Q - 1), slot = tid / Q;
  int node = blockIdx.x * NS + slot;
  if (node >= n) return;
  const ushort4* h4 = (const ushort4*)hlin;
  int start = rowptr[node], end = rowptr[node + 1];
  float di = dinv[node];
  float ax = 0.f, ay = 0.f, az = 0.f, aw = 0.f;
  int j = start;
  for (; j + 3 < end; j += 4) {
    int s0 = csr_src[j], s1 = csr_src[j + 1], s2 = csr_src[j + 2], s3 = csr_src[j + 3];
    float w0 = dinv[s0] * di, w1 = dinv[s1] * di, w2 = dinv[s2] * di, w3 = dinv[s3] * di;
    ushort4 v0 = h4[(size_t)s0 * Q + tx];
    ushort4 v1 = h4[(size_t)s1 * Q + tx];
    ushort4 v2 = h4[(size_t)s2 * Q + tx];
    ushort4 v3 = h4[(size_t)s3 * Q + tx];
    ax += bf2f(v0.x) * w0 + bf2f(v1.x) * w1 + bf2f(v2.x) * w2 + bf2f(v3.x) * w3;
    ay += bf2f(v0.y) * w0 + bf2f(v1.y) * w1 + bf2f(v2.y) * w2 + bf2f(v3.y) * w3;
    az += bf2f(v0.z) * w0 + bf2f(v1.z) * w1 + bf2f(v2.z) * w2 + bf2f(v3.z) * w3;
    aw += bf2f(v0.w) * w0 + bf2f(v1.w) * w1 + bf2f(v2.w) * w2 + bf2f(v3.w) * w3;
  }
  for (; j < end; ++j) {
    int s0 = csr_src[j];
    float w0 = dinv[s0] * di;
    ushort4 v0 = h4[(size_t)s0 * Q + tx];
    ax += bf2f(v0.x) * w0; ay += bf2f(v0.y) * w0;
    az += bf2f(v0.z) * w0; aw += bf2f(v0.w) * w0;
  }
  float sw = di * di;
  ushort4 hv = h4[(size_t)node * Q + tx];
  float4 bv = ((const float4*)b)[tx];
  ushort4 o;
  o.x = f2bf(fmaxf(ax + bf2f(hv.x) * sw + bv.x, 0.f));
  o.y = f2bf(fmaxf(ay + bf2f(hv.y) * sw + bv.y, 0.f));
  o.z = f2bf(fmaxf(az + bf2f(hv.z) * sw + bv.z, 0.f));
  o.w = f2bf(fmaxf(aw + bf2f(hv.w) * sw + bv.w, 0.f));
  ((ushort4*)out)[(size_t)node * Q + tx] = o;
}

// ---------------- pool: batch sorted -> segment mean (bf16 in, fp32 out) ----------------
__global__ void gstart_kernel(const int* __restrict__ batch, int* __restrict__ gstart,
                              int n, int G) {
  int i = blockIdx.x * TPB + threadIdx.x;
  if (i >= n) return;
  int bi = batch[i];
  int bp = (i == 0) ? -1 : batch[i - 1];
  for (int g = bp + 1; g <= bi; ++g) gstart[g] = i;
  if (i == n - 1)
    for (int g = bi + 1; g <= G; ++g) gstart[g] = n;
}

__global__ __launch_bounds__(256) void pool2_kernel(
    const ushort* __restrict__ h, const int* __restrict__ gstart,
    float* __restrict__ out) {
  __shared__ float sh[4][LAT];
  int g = blockIdx.x;
  int s = gstart[g], epos = gstart[g + 1];
  int c = threadIdx.x & (LAT - 1), r = threadIdx.x >> 6;
  float acc = 0.f;
  for (int i = s + r; i < epos; i += 4)
    acc += bf2f(h[(size_t)i * LAT + c]);
  sh[r][c] = acc;
  __syncthreads();
  if (r == 0) {
    float v = sh[0][c] + sh[1][c] + sh[2][c] + sh[3][c];
    out[(size_t)g * LAT + c] = v / fmaxf((float)(epos - s), 1.f);
  }
}

extern "C" void kernel_launch(void* const* d_in, const int* in_sizes, int n_in,
                              void* d_out, int out_size, void* d_ws, size_t ws_size,
                              hipStream_t stream) {
  const float* x     = (const float*)d_in[0];
  const float* W_emb = (const float*)d_in[1];
  const float* b_emb = (const float*)d_in[2];
  const float* W1    = (const float*)d_in[3];
  const float* b1    = (const float*)d_in[4];
  const float* W2    = (const float*)d_in[5];
  const float* b2    = (const float*)d_in[6];
  const int*   ei    = (const int*)d_in[7];
  const int*   batch = (const int*)d_in[8];
  const int n = in_sizes[8];
  const int e = in_sizes[7] / 2;
  const int* srcp = ei;
  const int* dstp = ei + e;
  float* out = (float*)d_out;

  char* ws = (char*)d_ws;
  size_t off = 0;
  auto alloc = [&](size_t bytes) {
    void* p = ws + off;
    off += (bytes + 255) & ~(size_t)255;
    return p;
  };
  ushort* bufA    = (ushort*)alloc((size_t)n * HID * 2);   // h0 / h1 / h2 (bf16)
  ushort* bufB    = (ushort*)alloc((size_t)n * HID * 2);   // hlin (bf16)
  float*  dinv    = (float*)alloc((size_t)n * 4);
  int*    cnt     = (int*)alloc((size_t)n * 4);
  int*    rowptr  = (int*)alloc((size_t)(n + 1) * 4);
  int*    bsum    = (int*)alloc((size_t)512 * 4);
  int*    rank    = (int*)alloc((size_t)e * 4);
  int*    csr_src = (int*)alloc((size_t)e * 4);
  int*    gstart  = (int*)alloc((size_t)(GG + 1) * 4);

  const int nb = (n + TPB - 1) / TPB;
  const int eb = (e + TPB - 1) / TPB;
  const int mb = (n + 63) / 64;          // MFMA blocks: 64 nodes each

  hipMemsetAsync(cnt, 0, (size_t)n * 4, stream);

  // h0 = relu(x @ W_emb + b_emb) -> bufA (bf16)
  embed_kernel<<<2048, TPB, 0, stream>>>(x, W_emb, b_emb, bufA, n);

  // CSR by dst (counting sort, atomic-free placement) + dinv
  deg_rank_kernel<<<eb, TPB, 0, stream>>>(dstp, cnt, rank, e);
  dinv_kernel<<<nb, TPB, 0, stream>>>(cnt, dinv, n);
  scan1_kernel<<<nb, TPB, 0, stream>>>(cnt, rowptr, bsum, n);
  scan2_kernel<<<1, 512, 0, stream>>>(bsum, nb);
  scan3_kernel<<<nb, TPB, 0, stream>>>(rowptr, bsum, n, e);
  place_kernel<<<eb, TPB, 0, stream>>>(srcp, dstp, rowptr, rank, csr_src, e);

  // graph segment starts (batch sorted)
  gstart_kernel<<<nb, TPB, 0, stream>>>(batch, gstart, n, GG);

  // conv1: MFMA lin -> bufB; gather(+self+bias+relu) -> bufA
  lin_mfma_kernel<HID><<<mb, TPB, 0, stream>>>(bufA, W1, bufB, n);
  gather_kernel<HID><<<(n * (HID / 4) + TPB - 1) / TPB, TPB, 0, stream>>>(
      bufB, rowptr, csr_src, dinv, b1, bufA, n);

  // conv2: MFMA lin -> bufB (n x 64); gather -> bufA (n x 64)
  lin_mfma_kernel<LAT><<<mb, TPB, 0, stream>>>(bufA, W2, bufB, n);
  gather_kernel<LAT><<<(n * (LAT / 4) + TPB - 1) / TPB, TPB, 0, stream>>>(
      bufB, rowptr, csr_src, dinv, b2, bufA, n);

  // mean pool
  pool2_kernel<<<GG, TPB, 0, stream>>>(bufA, gstart, out);
}